// Round 21
// baseline (51.115 us; speedup 1.0000x reference)
//
#include <hip/hip_runtime.h>
#include <math.h>

// Gaussian KDE, n=12000. ONE dispatch. Mean-matched binned KDE (1-level FGT)
// with FULLY REDUNDANT per-block preprocessing:
//   kde_all 188x256: every block independently
//     pass1: min/max + stats (s1,s2,sd,sd2) over ALL n (fixed-order reduce ->
//            bitwise-identical params in every block; data is L2-resident)
//     pass2: private LDS 2048-bin hist(int)/W/WE via LDS atomics over ALL n
//     scan 2048 bins; Q25/Q75 by within-bin linear interpolation; Silverman h
//     transform bins -> sb[b]=(mu_b*rr, W_b*wsc)
//     evaluate own 64 outputs: pdf_i = sum_{b in +-delta window}
//            W'_b * exp2(-(e_i-mu_b)^2);  out[i] = log(pdf+1e-10)
// Rationale: R18-R20 established dispatch overhead ~5us each while all kernel
// work sums to ~9us; redundant recompute (R20's k3 trick, taken to the limit)
// trades cheap parallel L2 reads for 2 dispatch boundaries.
// Accuracy: mean-matched bins kill the linear Taylor term (log err ~0.002);
// interp quantile adds <=0.004; absmax ~0.008 vs threshold 0.1625.
// Determinism: all cross-element reductions fixed-order; int hist order-
// independent; float LDS-atomic W/WE ulp noise accepted (harness absmax).

#define BLK 256
#define NB 2048
#define CUT 4.0f

#if defined(__has_builtin)
#if __has_builtin(__builtin_amdgcn_exp2f)
#define EXP2(x) __builtin_amdgcn_exp2f(x)
#endif
#endif
#ifndef EXP2
#define EXP2(x) exp2f(x)
#endif

__global__ __launch_bounds__(BLK) void kde_all(const float* __restrict__ d,
                                               const float* __restrict__ w,
                                               float* __restrict__ out, int n) {
    __shared__ int   hist[NB];     // 8 KB (-> cum in place after scan)
    __shared__ float lW[NB];       // 8 KB
    __shared__ float lWE[NB];      // 8 KB
    __shared__ float2 sb[NB];      // 16 KB (mu*rr, W*wsc)
    __shared__ float4 sstat[4];
    __shared__ float2 smm[4];
    __shared__ int woff[4];
    __shared__ int tbin[4], tprev[4];
    __shared__ float spar[4];      // rr, wsc, delta
    __shared__ float sred[BLK];
    const int t = threadIdx.x, lane = t & 63, wv = t >> 6;

    #pragma unroll
    for (int k = 0; k < 8; ++k) {
        int b = t + k * BLK;
        hist[b] = 0; lW[b] = 0.f; lWE[b] = 0.f;
    }

    // ---- pass 1: min/max + stats over all n (fixed order) ----
    float s1 = 0.f, s2 = 0.f, sd = 0.f, sd2 = 0.f;
    float mn = __int_as_float(0x7f800000), mx = __int_as_float(0xff800000);
    for (int i = t; i < n; i += BLK) {
        float dv = d[i], wt = w[i];
        s1 += wt; s2 += wt * wt; sd += dv; sd2 += dv * dv;
        mn = fminf(mn, dv); mx = fmaxf(mx, dv);
    }
    for (int off = 32; off > 0; off >>= 1) {
        s1 += __shfl_down(s1, off); s2 += __shfl_down(s2, off);
        sd += __shfl_down(sd, off); sd2 += __shfl_down(sd2, off);
        mn = fminf(mn, __shfl_down(mn, off));
        mx = fmaxf(mx, __shfl_down(mx, off));
    }
    if (lane == 0) { sstat[wv] = make_float4(s1, s2, sd, sd2); smm[wv] = make_float2(mn, mx); }
    __syncthreads();
    // every thread: order-exact min/max reduce (identical in all blocks)
    float lo = smm[0].x, hi = smm[0].y;
    #pragma unroll
    for (int q = 1; q < 4; ++q) { lo = fminf(lo, smm[q].x); hi = fmaxf(hi, smm[q].y); }
    const float range = hi - lo;
    const float scale = (range > 0.f) ? (float)NB / range : 0.f;
    const float binw = (scale > 0.f) ? 1.0f / scale : 0.f;

    // ---- pass 2: bin all n into private LDS hist/W/WE ----
    for (int i = t; i < n; i += BLK) {
        float dv = d[i], wt = w[i];
        int b = (int)((dv - lo) * scale);
        b = b < NB ? b : NB - 1;
        atomicAdd(&hist[b], 1);
        atomicAdd(&lW[b], wt);
        atomicAdd(&lWE[b], wt * dv);
    }
    __syncthreads();

    // ---- in-block inclusive scan of 2048-bin hist (8 bins/thread) ----
    const int base = t * 8;
    int h8[8], pre[8];
    int s = 0;
    #pragma unroll
    for (int k = 0; k < 8; ++k) {
        h8[k] = hist[base + k];
        s += h8[k];
        pre[k] = s;
    }
    int v = s;
    for (int off = 1; off < 64; off <<= 1) {
        int u = __shfl_up(v, off);
        if (lane >= off) v += u;
    }
    if (lane == 63) woff[wv] = v;
    __syncthreads();
    int wexcl = 0;
    #pragma unroll
    for (int q = 0; q < 4; ++q) if (q < wv) wexcl += woff[q];
    const int texcl = wexcl + (v - s);         // exclusive prefix at 'base'
    #pragma unroll
    for (int k = 0; k < 8; ++k) hist[base + k] = texcl + pre[k];  // cum in place

    // ---- locate 4 target ranks within own 8 bins ----
    const double p25 = 0.25 * (double)(n - 1);
    const double p75 = 0.75 * (double)(n - 1);
    const int l25 = (int)p25, l75 = (int)p75;
    const int u25 = (l25 + 1 < n) ? l25 + 1 : l25;
    const int u75 = (l75 + 1 < n) ? l75 + 1 : l75;
    const int targets[4] = {l25, u25, l75, u75};
    #pragma unroll
    for (int k = 0; k < 8; ++k) {
        int prev = texcl + (k ? pre[k - 1] : 0);
        int incl = texcl + pre[k];
        #pragma unroll
        for (int r = 0; r < 4; ++r)
            if (prev <= targets[r] && targets[r] < incl) { tbin[r] = base + k; tprev[r] = prev; }
    }
    __syncthreads();

    // ---- h (t0, then broadcast) ----
    if (t == 0) {
        float qv[4];
        #pragma unroll
        for (int r = 0; r < 4; ++r) {
            int b = tbin[r];
            int cnt = hist[b] - tprev[r];      // hist holds cum now
            float pos = (float)b + ((float)(targets[r] - tprev[r]) + 0.5f) / (float)cnt;
            qv[r] = lo + pos * binw;
        }
        double S1 = 0, S2 = 0, Sd = 0, Sd2 = 0;
        #pragma unroll
        for (int q = 0; q < 4; ++q) {
            float4 a = sstat[q];
            S1 += a.x; S2 += a.y; Sd += a.z; Sd2 += a.w;
        }
        float neff = (float)(S1 * S1 / S2);
        float varf = (float)((Sd2 - Sd * Sd / (double)n) / ((double)n - 1.0));
        float sdev = sqrtf(varf);
        float f25 = (float)(p25 - (double)l25), f75 = (float)(p75 - (double)l75);
        float q25 = qv[0] + f25 * (qv[1] - qv[0]);
        float q75 = qv[2] + f75 * (qv[3] - qv[2]);
        float sig = fminf(sdev, (q75 - q25) * (1.0f / 1.34f));
        float hb = 0.9f * sig * exp2f(-0.2f * log2f(neff));
        float rr = 0.84932180f / hb;                        // sqrt(0.5*log2(e))/h
        float wsc = 1.0f / (hb * 2.50662827f * (float)S1);  // inv_norm / S1
        float delta = (scale > 0.f && rr > 0.f)
                      ? ceilf(CUT * scale / rr) + 2.0f : (float)NB;
        spar[0] = rr; spar[1] = wsc; spar[2] = delta;
    }
    __syncthreads();
    const float rr = spar[0], wsc = spar[1];
    const int delta = (int)spar[2];

    // ---- transform own bins -> sb ----
    #pragma unroll
    for (int k = 0; k < 8; ++k) {
        int b = base + k;
        float W = lW[b];
        float mu = (W > 0.f) ? (lWE[b] / W) : 0.f;
        sb[b] = make_float2(mu * rr, W * wsc);
    }
    __syncthreads();

    // ---- evaluate own 64 outputs: 4-way wave split of the window ----
    const int i = blockIdx.x * 64 + lane;
    const float di = (i < n) ? d[i] : 0.f;
    const float ei = di * rr;
    int bi = (int)((di - lo) * scale);
    bi = bi < NB ? bi : NB - 1; if (bi < 0) bi = 0;
    int b0 = bi - delta; if (b0 < 0) b0 = 0;
    int b1 = bi + delta; if (b1 > NB - 1) b1 = NB - 1;
    const int len = b1 - b0 + 1;
    const int q = (len + 3) >> 2;
    int ws_ = b0 + wv * q;
    int we_ = ws_ + q; if (we_ > b1 + 1) we_ = b1 + 1;

    float acc0 = 0.f, acc1 = 0.f;
    int b = ws_;
    for (; b + 1 < we_; b += 2) {
        float2 p0 = sb[b], p1 = sb[b + 1];
        float u0 = ei - p0.x, u1 = ei - p1.x;
        acc0 = fmaf(p0.y, EXP2(-(u0 * u0)), acc0);
        acc1 = fmaf(p1.y, EXP2(-(u1 * u1)), acc1);
    }
    if (b < we_) {
        float2 p0 = sb[b];
        float u0 = ei - p0.x;
        acc0 = fmaf(p0.y, EXP2(-(u0 * u0)), acc0);
    }

    sred[wv * 64 + lane] = acc0 + acc1;
    __syncthreads();
    if (t < 64) {
        int ii = blockIdx.x * 64 + t;
        if (ii < n) {
            float p = sred[t] + sred[64 + t] + sred[128 + t] + sred[192 + t];
            out[ii] = logf(p + 1e-10f);
        }
    }
}

extern "C" void kernel_launch(void* const* d_in, const int* in_sizes, int n_in,
                              void* d_out, int out_size, void* d_ws, size_t ws_size,
                              hipStream_t stream) {
    const float* d = (const float*)d_in[0];
    const float* w = (const float*)d_in[1];
    float* out = (float*)d_out;
    const int n = in_sizes[0];

    const int nmax = ((n + 63) / 64) * 64;   // 12032
    const int G = nmax / 64;                 // 188 blocks, 64 outputs each

    kde_all<<<G, BLK, 0, stream>>>(d, w, out, n);
}

// Round 22
// 50.376 us; speedup vs baseline: 1.0147x; 1.0147x over previous
//
#include <hip/hip_runtime.h>
#include <math.h>

// Gaussian KDE, n=12000. ONE dispatch, mean-matched binned KDE (1-level FGT),
// fully-redundant per-block preprocessing with LATENCY-BATCHED loops:
//   kde_all 188x256 (~138KB LDS, 1 block/CU): every block independently
//     pass1: chunk-8 register-prefetched global reads (16 loads in flight) ->
//            stats+min/max partials; stage (d,w) into LDS sdw[n]
//     pass2: chunk-8 LDS re-read of OWN elements -> 2048-bin hist/W/WE
//            via LDS atomics (no cross-thread dependency until reduce)
//     scan 2048 bins; Q25/Q75 by within-bin interpolation; Silverman h
//     transform bins -> sb[b]=(mu_b*rr, W_b*wsc)
//     evaluate own 64 outputs over the +-delta bin window; out=log(pdf+1e-10)
// R21 lesson: strided O(n) loops cost ~1 round-trip PER ITERATION when not
// batched; chunk-8 prefetch cuts pass stalls ~8x. OV ~5us/dispatch (R18-R20
// fit) makes 1 dispatch optimal if per-block work is ~5us.
// Accuracy: mean-matched bins (log err ~0.002) + interp quantile (<=0.004)
// vs threshold 0.1625. Float LDS-atomic ulp noise accepted (since R17).

#define BLK 256
#define NB 2048
#define MAXN 12032
#define CUT 4.0f

#if defined(__has_builtin)
#if __has_builtin(__builtin_amdgcn_exp2f)
#define EXP2(x) __builtin_amdgcn_exp2f(x)
#endif
#endif
#ifndef EXP2
#define EXP2(x) exp2f(x)
#endif

__global__ __launch_bounds__(BLK) void kde_all(const float* __restrict__ d,
                                               const float* __restrict__ w,
                                               float* __restrict__ out, int n) {
    __shared__ float2 sdw[MAXN];   // 96.3 KB staged (d,w)
    __shared__ int   hist[NB];     // 8 KB (-> cum in place after scan)
    __shared__ float lW[NB];       // 8 KB
    __shared__ float lWE[NB];      // 8 KB
    __shared__ float2 sb[NB];      // 16 KB (mu*rr, W*wsc)
    __shared__ float4 sstat[4];
    __shared__ float2 smm[4];
    __shared__ int woff[4];
    __shared__ int tbin[4], tprev[4];
    __shared__ float spar[4];      // rr, wsc, delta
    __shared__ float sred[BLK];
    const int t = threadIdx.x, lane = t & 63, wv = t >> 6;

    #pragma unroll
    for (int k = 0; k < 8; ++k) {
        int b = t + k * BLK;
        hist[b] = 0; lW[b] = 0.f; lWE[b] = 0.f;
    }

    const int niter = (n + BLK - 1) / BLK;   // 47

    // ---- pass 1: chunk-8 prefetched global reads; stats+minmax; stage LDS ----
    float s1 = 0.f, s2 = 0.f, sd = 0.f, sd2 = 0.f;
    float mn = __int_as_float(0x7f800000), mx = __int_as_float(0xff800000);
    for (int c0 = 0; c0 < niter; c0 += 8) {
        float dv[8], wt[8];
        #pragma unroll
        for (int k = 0; k < 8; ++k) {           // 16 loads issued back-to-back
            int i = (c0 + k) * BLK + t;
            bool ok = (i < n);
            dv[k] = ok ? d[i] : 0.f;
            wt[k] = ok ? w[i] : 0.f;
        }
        #pragma unroll
        for (int k = 0; k < 8; ++k) {
            int i = (c0 + k) * BLK + t;
            if (i < n) {
                sdw[i] = make_float2(dv[k], wt[k]);
                s1 += wt[k]; s2 += wt[k] * wt[k];
                sd += dv[k]; sd2 += dv[k] * dv[k];
                mn = fminf(mn, dv[k]); mx = fmaxf(mx, dv[k]);
            }
        }
    }
    for (int off = 32; off > 0; off >>= 1) {
        s1 += __shfl_down(s1, off); s2 += __shfl_down(s2, off);
        sd += __shfl_down(sd, off); sd2 += __shfl_down(sd2, off);
        mn = fminf(mn, __shfl_down(mn, off));
        mx = fmaxf(mx, __shfl_down(mx, off));
    }
    if (lane == 0) { sstat[wv] = make_float4(s1, s2, sd, sd2); smm[wv] = make_float2(mn, mx); }
    __syncthreads();
    // order-exact min/max reduce: identical in every thread & block
    float lo = smm[0].x, hi = smm[0].y;
    #pragma unroll
    for (int q = 1; q < 4; ++q) { lo = fminf(lo, smm[q].x); hi = fmaxf(hi, smm[q].y); }
    const float range = hi - lo;
    const float scale = (range > 0.f) ? (float)NB / range : 0.f;
    const float binw = (scale > 0.f) ? 1.0f / scale : 0.f;

    // ---- pass 2: chunk-8 LDS re-read (own elements only); bin via LDS atomics ----
    for (int c0 = 0; c0 < niter; c0 += 8) {
        float2 v8[8];
        #pragma unroll
        for (int k = 0; k < 8; ++k) {
            int i = (c0 + k) * BLK + t;
            v8[k] = (i < n) ? sdw[i] : make_float2(0.f, 0.f);
        }
        #pragma unroll
        for (int k = 0; k < 8; ++k) {
            int i = (c0 + k) * BLK + t;
            if (i < n) {
                float dv = v8[k].x, wt = v8[k].y;
                int b = (int)((dv - lo) * scale);
                b = b < NB ? b : NB - 1;
                atomicAdd(&hist[b], 1);
                atomicAdd(&lW[b], wt);
                atomicAdd(&lWE[b], wt * dv);
            }
        }
    }
    __syncthreads();

    // ---- in-block inclusive scan of 2048-bin hist (8 bins/thread) ----
    const int base = t * 8;
    int h8[8], pre[8];
    int s = 0;
    #pragma unroll
    for (int k = 0; k < 8; ++k) {
        h8[k] = hist[base + k];
        s += h8[k];
        pre[k] = s;
    }
    int v = s;
    for (int off = 1; off < 64; off <<= 1) {
        int u = __shfl_up(v, off);
        if (lane >= off) v += u;
    }
    if (lane == 63) woff[wv] = v;
    __syncthreads();
    int wexcl = 0;
    #pragma unroll
    for (int q = 0; q < 4; ++q) if (q < wv) wexcl += woff[q];
    const int texcl = wexcl + (v - s);
    #pragma unroll
    for (int k = 0; k < 8; ++k) hist[base + k] = texcl + pre[k];  // cum in place

    // ---- locate 4 target ranks within own 8 bins ----
    const double p25 = 0.25 * (double)(n - 1);
    const double p75 = 0.75 * (double)(n - 1);
    const int l25 = (int)p25, l75 = (int)p75;
    const int u25 = (l25 + 1 < n) ? l25 + 1 : l25;
    const int u75 = (l75 + 1 < n) ? l75 + 1 : l75;
    const int targets[4] = {l25, u25, l75, u75};
    #pragma unroll
    for (int k = 0; k < 8; ++k) {
        int prev = texcl + (k ? pre[k - 1] : 0);
        int incl = texcl + pre[k];
        #pragma unroll
        for (int r = 0; r < 4; ++r)
            if (prev <= targets[r] && targets[r] < incl) { tbin[r] = base + k; tprev[r] = prev; }
    }
    __syncthreads();

    // ---- h (t0, then broadcast) ----
    if (t == 0) {
        float qv[4];
        #pragma unroll
        for (int r = 0; r < 4; ++r) {
            int b = tbin[r];
            int cnt = hist[b] - tprev[r];
            float pos = (float)b + ((float)(targets[r] - tprev[r]) + 0.5f) / (float)cnt;
            qv[r] = lo + pos * binw;
        }
        double S1 = 0, S2 = 0, Sd = 0, Sd2 = 0;
        #pragma unroll
        for (int q = 0; q < 4; ++q) {
            float4 a = sstat[q];
            S1 += a.x; S2 += a.y; Sd += a.z; Sd2 += a.w;
        }
        float neff = (float)(S1 * S1 / S2);
        float varf = (float)((Sd2 - Sd * Sd / (double)n) / ((double)n - 1.0));
        float sdev = sqrtf(varf);
        float f25 = (float)(p25 - (double)l25), f75 = (float)(p75 - (double)l75);
        float q25 = qv[0] + f25 * (qv[1] - qv[0]);
        float q75 = qv[2] + f75 * (qv[3] - qv[2]);
        float sig = fminf(sdev, (q75 - q25) * (1.0f / 1.34f));
        float hb = 0.9f * sig * exp2f(-0.2f * log2f(neff));
        float rr = 0.84932180f / hb;                        // sqrt(0.5*log2(e))/h
        float wsc = 1.0f / (hb * 2.50662827f * (float)S1);  // inv_norm / S1
        float delta = (scale > 0.f && rr > 0.f)
                      ? ceilf(CUT * scale / rr) + 2.0f : (float)NB;
        spar[0] = rr; spar[1] = wsc; spar[2] = delta;
    }
    __syncthreads();
    const float rr = spar[0], wsc = spar[1];
    const int delta = (int)spar[2];

    // ---- transform own bins -> sb ----
    #pragma unroll
    for (int k = 0; k < 8; ++k) {
        int b = base + k;
        float W = lW[b];
        float mu = (W > 0.f) ? (lWE[b] / W) : 0.f;
        sb[b] = make_float2(mu * rr, W * wsc);
    }
    __syncthreads();

    // ---- evaluate own 64 outputs: 4-way wave split of the window ----
    const int i = blockIdx.x * 64 + lane;
    const float di = (i < n) ? sdw[i].x : 0.f;
    const float ei = di * rr;
    int bi = (int)((di - lo) * scale);
    bi = bi < NB ? bi : NB - 1; if (bi < 0) bi = 0;
    int b0 = bi - delta; if (b0 < 0) b0 = 0;
    int b1 = bi + delta; if (b1 > NB - 1) b1 = NB - 1;
    const int len = b1 - b0 + 1;
    const int q = (len + 3) >> 2;
    int ws_ = b0 + wv * q;
    int we_ = ws_ + q; if (we_ > b1 + 1) we_ = b1 + 1;

    float acc0 = 0.f, acc1 = 0.f;
    int b = ws_;
    for (; b + 1 < we_; b += 2) {
        float2 p0 = sb[b], p1 = sb[b + 1];
        float u0 = ei - p0.x, u1 = ei - p1.x;
        acc0 = fmaf(p0.y, EXP2(-(u0 * u0)), acc0);
        acc1 = fmaf(p1.y, EXP2(-(u1 * u1)), acc1);
    }
    if (b < we_) {
        float2 p0 = sb[b];
        float u0 = ei - p0.x;
        acc0 = fmaf(p0.y, EXP2(-(u0 * u0)), acc0);
    }

    sred[wv * 64 + lane] = acc0 + acc1;
    __syncthreads();
    if (t < 64) {
        int ii = blockIdx.x * 64 + t;
        if (ii < n) {
            float p = sred[t] + sred[64 + t] + sred[128 + t] + sred[192 + t];
            out[ii] = logf(p + 1e-10f);
        }
    }
}

extern "C" void kernel_launch(void* const* d_in, const int* in_sizes, int n_in,
                              void* d_out, int out_size, void* d_ws, size_t ws_size,
                              hipStream_t stream) {
    const float* d = (const float*)d_in[0];
    const float* w = (const float*)d_in[1];
    float* out = (float*)d_out;
    const int n = in_sizes[0];

    const int nmax = ((n + 63) / 64) * 64;   // 12032
    const int G = nmax / 64;                 // 188 blocks, 64 outputs each

    kde_all<<<G, BLK, 0, stream>>>(d, w, out, n);
}

// Round 23
// 30.790 us; speedup vs baseline: 1.6601x; 1.6361x over previous
//
#include <hip/hip_runtime.h>
#include <math.h>

// Gaussian KDE, n=12000. TWO dispatches, mean-matched binned KDE (FGT).
//   prep_k 12x1024: zero bins; 1 elem/thread stats+minmax -> statP/mmP;
//      release fence + per-block MAGIC flag; t0 spins for all 12 flags
//      (12 co-resident blocks -> bounded, no deadlock); acquire; lo/scale
//      (order-exact); bin own element via 3 device atomicAdds (gH/gW/gWE).
//   eval_k 188x256: reset flags (block 0); redundant finalize per block
//      (scan gH, interp quantiles, Silverman h) + windowed evaluation:
//      pdf_i = sum_b W'_b * exp2(-(e_i-mu_b)^2); out[i]=log(pdf+1e-10).
// R18/R21/R22 lesson: per-block redundant O(n) costs ~45us; R20's 3-dispatch
// = ~7us kernels + ~17us dispatch OV. This removes one OV via an internal
// producer barrier over only 12 blocks (all resident; R4-validated fence
// pattern; flags reset by eval_k, stream-ordered before next replay's prep).
// Accuracy: mean-matched bins (log err ~0.002) + interp quantile (<=0.004)
// vs threshold 0.1625. Float atomic ulp noise accepted (since R17).

#define BLK 256
#define NB 2048
#define NPART 12
#define CUT 4.0f
#define MAGIC 0x13579BDF

#if defined(__has_builtin)
#if __has_builtin(__builtin_amdgcn_exp2f)
#define EXP2(x) __builtin_amdgcn_exp2f(x)
#endif
#endif
#ifndef EXP2
#define EXP2(x) exp2f(x)
#endif

__global__ __launch_bounds__(1024) void prep_k(const float* __restrict__ d,
                                               const float* __restrict__ w,
                                               float4* __restrict__ statP,
                                               float2* __restrict__ mmP,
                                               int* __restrict__ flagA,
                                               float* __restrict__ gZero,  // 3*NB words
                                               int* __restrict__ gH,
                                               float* __restrict__ gW,
                                               float* __restrict__ gWE,
                                               int n) {
    __shared__ float4 sstat[16];
    __shared__ float2 smm[16];
    const int t = threadIdx.x, lane = t & 63, wid = t >> 6, blk = blockIdx.x;

    // zero this block's slice of the global accumulators (12*512 = 3*NB)
    if (t < 512) gZero[blk * 512 + t] = 0.f;

    const int i = blk * 1024 + t;
    const bool ok = (i < n);
    float dv = ok ? d[i] : 0.f;
    float wv = ok ? w[i] : 0.f;
    float mn = ok ? dv : __int_as_float(0x7f800000);
    float mx = ok ? dv : __int_as_float(0xff800000);
    float s1 = wv, s2 = wv * wv, sd = dv, sd2 = dv * dv;
    for (int off = 32; off > 0; off >>= 1) {
        s1 += __shfl_down(s1, off); s2 += __shfl_down(s2, off);
        sd += __shfl_down(sd, off); sd2 += __shfl_down(sd2, off);
        mn = fminf(mn, __shfl_down(mn, off));
        mx = fmaxf(mx, __shfl_down(mx, off));
    }
    if (lane == 0) { sstat[wid] = make_float4(s1, s2, sd, sd2); smm[wid] = make_float2(mn, mx); }
    __syncthreads();   // also drains all threads' global stores (zeroes) pre-barrier
    if (t == 0) {
        float4 a = sstat[0]; float2 m = smm[0];
        for (int q = 1; q < 16; ++q) {
            float4 b = sstat[q];
            a.x += b.x; a.y += b.y; a.z += b.z; a.w += b.w;
            m.x = fminf(m.x, smm[q].x); m.y = fmaxf(m.y, smm[q].y);
        }
        statP[blk] = a;
        mmP[blk] = m;
        __threadfence();                       // release: zeroes + partials
        atomicExch(&flagA[blk], MAGIC);        // publish
        // spin until all 12 producers have published (all co-resident)
        for (int j = 0; j < NPART; ++j) {
            while (atomicCAS(&flagA[j], MAGIC, MAGIC) != MAGIC)
                __builtin_amdgcn_s_sleep(16);
        }
    }
    __syncthreads();
    __threadfence();                           // acquire

    // lo/scale: order-exact reduction, identical in every thread/block
    float lo = __int_as_float(0x7f800000), hi = __int_as_float(0xff800000);
    #pragma unroll
    for (int p = 0; p < NPART; ++p) {
        float2 m = mmP[p];
        lo = fminf(lo, m.x); hi = fmaxf(hi, m.y);
    }
    const float range = hi - lo;
    const float scale = (range > 0.f) ? (float)NB / range : 0.f;

    if (ok) {
        int b = (int)((dv - lo) * scale);
        b = b < NB ? b : NB - 1;
        atomicAdd(&gH[b], 1);
        atomicAdd(&gW[b], wv);
        atomicAdd(&gWE[b], wv * dv);
    }
}

__global__ __launch_bounds__(BLK) void eval_k(const float* __restrict__ d,
                                              const float4* __restrict__ statP,
                                              const float2* __restrict__ mmP,
                                              int* __restrict__ flagA,
                                              const int* __restrict__ gH,
                                              const float* __restrict__ gW,
                                              const float* __restrict__ gWE,
                                              float* __restrict__ out, int n) {
    __shared__ float2 sb[NB];     // 16 KB  (mu*rr, W*wsc)
    __shared__ int cum[NB];       // 8 KB
    __shared__ int woff[4];
    __shared__ int tbin[4], tprev[4];
    __shared__ float spar[4];
    __shared__ float sred[BLK];
    const int t = threadIdx.x, lane = t & 63, wv = t >> 6;

    if (blockIdx.x == 0 && t < NPART) flagA[t] = 0;   // reset for next replay

    // lo/scale (order-exact, every thread)
    float lo = __int_as_float(0x7f800000), hi = __int_as_float(0xff800000);
    #pragma unroll
    for (int p = 0; p < NPART; ++p) {
        float2 m = mmP[p];
        lo = fminf(lo, m.x); hi = fmaxf(hi, m.y);
    }
    const float range = hi - lo;
    const float scale = (range > 0.f) ? (float)NB / range : 0.f;
    const float binw = (scale > 0.f) ? 1.0f / scale : 0.f;

    // load hist + raw moments; in-block scan of 2048 bins (8 bins/thread)
    const int base = t * 8;
    int h8[8], pre[8];
    int s = 0;
    #pragma unroll
    for (int k = 0; k < 8; ++k) {
        int b = base + k;
        h8[k] = gH[b];
        sb[b] = make_float2(gWE[b], gW[b]);   // raw (WE, W)
        s += h8[k];
        pre[k] = s;
    }
    int v = s;
    for (int off = 1; off < 64; off <<= 1) {
        int u = __shfl_up(v, off);
        if (lane >= off) v += u;
    }
    if (lane == 63) woff[wv] = v;
    __syncthreads();
    int wexcl = 0;
    #pragma unroll
    for (int q = 0; q < 4; ++q) if (q < wv) wexcl += woff[q];
    const int texcl = wexcl + (v - s);
    #pragma unroll
    for (int k = 0; k < 8; ++k) cum[base + k] = texcl + pre[k];

    // locate 4 target ranks within own 8 bins
    const double p25 = 0.25 * (double)(n - 1);
    const double p75 = 0.75 * (double)(n - 1);
    const int l25 = (int)p25, l75 = (int)p75;
    const int u25 = (l25 + 1 < n) ? l25 + 1 : l25;
    const int u75 = (l75 + 1 < n) ? l75 + 1 : l75;
    const int targets[4] = {l25, u25, l75, u75};
    #pragma unroll
    for (int k = 0; k < 8; ++k) {
        int prev = texcl + (k ? pre[k - 1] : 0);
        int incl = texcl + pre[k];
        #pragma unroll
        for (int r = 0; r < 4; ++r)
            if (prev <= targets[r] && targets[r] < incl) { tbin[r] = base + k; tprev[r] = prev; }
    }
    __syncthreads();

    if (t == 0) {
        float qv[4];
        #pragma unroll
        for (int r = 0; r < 4; ++r) {
            int b = tbin[r];
            int cnt = cum[b] - tprev[r];
            float pos = (float)b + ((float)(targets[r] - tprev[r]) + 0.5f) / (float)cnt;
            qv[r] = lo + pos * binw;
        }
        double S1 = 0, S2 = 0, Sd = 0, Sd2 = 0;
        #pragma unroll
        for (int p = 0; p < NPART; ++p) {
            float4 a = statP[p];
            S1 += a.x; S2 += a.y; Sd += a.z; Sd2 += a.w;
        }
        float neff = (float)(S1 * S1 / S2);
        float varf = (float)((Sd2 - Sd * Sd / (double)n) / ((double)n - 1.0));
        float sdev = sqrtf(varf);
        float f25 = (float)(p25 - (double)l25), f75 = (float)(p75 - (double)l75);
        float q25 = qv[0] + f25 * (qv[1] - qv[0]);
        float q75 = qv[2] + f75 * (qv[3] - qv[2]);
        float sig = fminf(sdev, (q75 - q25) * (1.0f / 1.34f));
        float hb = 0.9f * sig * exp2f(-0.2f * log2f(neff));
        float rr = 0.84932180f / hb;                        // sqrt(0.5*log2(e))/h
        float wsc = 1.0f / (hb * 2.50662827f * (float)S1);  // inv_norm / S1
        float delta = (scale > 0.f && rr > 0.f)
                      ? ceilf(CUT * scale / rr) + 2.0f : (float)NB;
        spar[0] = rr; spar[1] = wsc; spar[2] = delta;
    }
    __syncthreads();
    const float rr = spar[0], wsc = spar[1];
    const int delta = (int)spar[2];

    // transform own bins: (WE,W) -> (mu*rr, W*wsc)
    #pragma unroll
    for (int k = 0; k < 8; ++k) {
        int b = base + k;
        float2 vr = sb[b];
        float W = vr.y;
        float mu = (W > 0.f) ? (vr.x / W) : 0.f;
        sb[b] = make_float2(mu * rr, W * wsc);
    }
    __syncthreads();

    // evaluate own 64 outputs: 4-way wave split of the +-delta window
    const int i = blockIdx.x * 64 + lane;
    const float di = (i < n) ? d[i] : 0.f;
    const float ei = di * rr;
    int bi = (int)((di - lo) * scale);
    bi = bi < NB ? bi : NB - 1; if (bi < 0) bi = 0;
    int b0 = bi - delta; if (b0 < 0) b0 = 0;
    int b1 = bi + delta; if (b1 > NB - 1) b1 = NB - 1;
    const int len = b1 - b0 + 1;
    const int q = (len + 3) >> 2;
    int ws_ = b0 + wv * q;
    int we_ = ws_ + q; if (we_ > b1 + 1) we_ = b1 + 1;

    float acc0 = 0.f, acc1 = 0.f;
    int b = ws_;
    for (; b + 1 < we_; b += 2) {
        float2 p0 = sb[b], p1 = sb[b + 1];
        float u0 = ei - p0.x, u1 = ei - p1.x;
        acc0 = fmaf(p0.y, EXP2(-(u0 * u0)), acc0);
        acc1 = fmaf(p1.y, EXP2(-(u1 * u1)), acc1);
    }
    if (b < we_) {
        float2 p0 = sb[b];
        float u0 = ei - p0.x;
        acc0 = fmaf(p0.y, EXP2(-(u0 * u0)), acc0);
    }

    sred[wv * 64 + lane] = acc0 + acc1;
    __syncthreads();
    if (t < 64) {
        int ii = blockIdx.x * 64 + t;
        if (ii < n) {
            float p = sred[t] + sred[64 + t] + sred[128 + t] + sred[192 + t];
            out[ii] = logf(p + 1e-10f);
        }
    }
}

extern "C" void kernel_launch(void* const* d_in, const int* in_sizes, int n_in,
                              void* d_out, int out_size, void* d_ws, size_t ws_size,
                              hipStream_t stream) {
    const float* d = (const float*)d_in[0];
    const float* w = (const float*)d_in[1];
    float* out = (float*)d_out;
    const int n = in_sizes[0];

    const int nmax = ((n + 63) / 64) * 64;   // 12032
    const int G = nmax / 64;                 // 188

    // ws layout (floats): statP float4[12] (48) | mmP float2[12] (24) |
    //   flagA int[12]+pad (16) | gH int[NB] | gW[NB] | gWE[NB] (contiguous)
    float*  wsf   = (float*)d_ws;
    float4* statP = (float4*)wsf;
    float2* mmP   = (float2*)(wsf + 48);
    int*    flagA = (int*)(wsf + 72);
    float*  gZero = wsf + 88;
    int*    gH    = (int*)(wsf + 88);
    float*  gW    = wsf + 88 + NB;
    float*  gWE   = wsf + 88 + 2 * NB;

    prep_k<<<NPART, 1024, 0, stream>>>(d, w, statP, mmP, flagA, gZero, gH, gW, gWE, n);
    eval_k<<<G, BLK, 0, stream>>>(d, statP, mmP, flagA, gH, gW, gWE, out, n);
}